// Round 3
// baseline (249.176 us; speedup 1.0000x reference)
//
#include <hip/hip_runtime.h>

#define DIM 6
#define NSEG 65535
#define CH 64            // segments per chunk
#define NCHUNK 1024      // NCHUNK*CH >= NSEG

// Padded partial-signature layout (per chunk), stride in floats.
// All vector-load offsets 16B-aligned: L1@0(6), L2@8(36), L3@48(216), L4@264(1296)
#define PSTRIDE 1568
#define PL1 0
#define PL2 8
#define PL3 48
#define PL4 264

// ---------------- Kernel 1: one wave per chunk, register-resident Chen fold -
// Lane t<36 owns pair ab=t (a=ab/6, b=ab%6): S4 row [ab][*] (36 regs),
// S3 row [ab][*] (6 regs), S2[ab], and a private copy of S1[a].
// Per segment: 2 broadcast LDS reads (dx row), ~62 VALU, no writes, no barrier.
__global__ __launch_bounds__(64) void sig_fold(const float* __restrict__ x,
                                               float* __restrict__ part) {
    __shared__ float dxs[CH * 8];   // dx row j at 8-float stride (32B aligned)
    const int t = threadIdx.x;
    const int c = blockIdx.x;
    const int j0 = c * CH;
    const int cnt = min(CH, NSEG - j0);    // 64, or 63 for the last chunk

#pragma unroll
    for (int f = t; f < CH * 8; f += 64) dxs[f] = 0.f;
    __syncthreads();
    const float* xb = x + (size_t)j0 * DIM;
    for (int f = t; f < cnt * DIM; f += 64) {
        int j = f / 6, k = f - j * 6;
        dxs[j * 8 + k] = xb[f + 6] - xb[f];
    }
    __syncthreads();   // single-wave block: compiles to a cheap wait

    const int ab = (t < 36) ? t : 35;
    const int a = ab / 6, b = ab - a * 6;

    float r4[36], r3[6], r2 = 0.f, s1 = 0.f;
#pragma unroll
    for (int i = 0; i < 36; ++i) r4[i] = 0.f;
#pragma unroll
    for (int i = 0; i < 6; ++i) r3[i] = 0.f;

#pragma unroll 2
    for (int j = 0; j < CH; ++j) {
        const float4 q0 = *(const float4*)(dxs + j * 8);
        const float2 q1 = *(const float2*)(dxs + j * 8 + 4);
        float dx[6] = {q0.x, q0.y, q0.z, q0.w, q1.x, q1.y};
        float hdx[6];
#pragma unroll
        for (int i = 0; i < 6; ++i) hdx[i] = 0.5f * dx[i];

        // t2 = S2 + dx_b*(S1/3 + dx_a/12)   (old S2, S1)
        float t2 = fmaf(dx[b], fmaf(dx[a], (1.f / 12.f), s1 * (1.f / 3.f)), r2);
        // S4[cd] += (S3[c] + t2*hdx[c]) * dx[d]     (old S3)
        float w[6];
#pragma unroll
        for (int cc = 0; cc < 6; ++cc) w[cc] = fmaf(t2, hdx[cc], r3[cc]);
#pragma unroll
        for (int cc = 0; cc < 6; ++cc)
#pragma unroll
            for (int d = 0; d < 6; ++d)
                r4[cc * 6 + d] = fmaf(w[cc], dx[d], r4[cc * 6 + d]);
        // S3[c] += (S2 + t3*hdx_b) * dx[c],  t3 = S1 + dx_a/3   (old S2, S1)
        float t3 = fmaf(dx[a], (1.f / 3.f), s1);
        float v = fmaf(t3, hdx[b], r2);
#pragma unroll
        for (int cc = 0; cc < 6; ++cc) r3[cc] = fmaf(v, dx[cc], r3[cc]);
        // S2 += (S1 + hdx_a) * dx_b ; S1 += dx_a
        r2 = fmaf(s1 + hdx[a], dx[b], r2);
        s1 += dx[a];
    }

    if (t < 36) {
        float* P = part + (size_t)c * PSTRIDE;
        if (a == b) P[PL1 + a] = s1;
        P[PL2 + ab] = r2;
        float* p3 = P + PL3 + ab * 6;
        *(float2*)(p3 + 0) = make_float2(r3[0], r3[1]);
        *(float2*)(p3 + 2) = make_float2(r3[2], r3[3]);
        *(float2*)(p3 + 4) = make_float2(r3[4], r3[5]);
        float* p4 = P + PL4 + ab * 36;
#pragma unroll
        for (int i = 0; i < 9; ++i)
            *(float4*)(p4 + 4 * i) =
                make_float4(r4[4 * i], r4[4 * i + 1], r4[4 * i + 2], r4[4 * i + 3]);
    }
}

// ---------------- Kernel 2: register-resident sequential Chen combine -------
// Block g folds partials [g*R, (g+1)*R): Acc = Acc (x) U_r, same lane=ab
// ownership; B-side streamed from global (no LDS). flat_out selects d_out
// layout (unpadded 1554) vs padded PSTRIDE layout.
__global__ __launch_bounds__(64) void sig_comb(const float* __restrict__ in,
                                               float* __restrict__ out,
                                               int R, int flat_out) {
    const int t = threadIdx.x;
    const int ab = (t < 36) ? t : 35;
    const int a = ab / 6, b = ab - a * 6;
    const float* base = in + (size_t)blockIdx.x * R * PSTRIDE;

    float r4[36], r3[6], r2, s1;
    {
        const float* P = base;
        s1 = P[PL1 + a];
        r2 = P[PL2 + ab];
        const float* p3 = P + PL3 + ab * 6;
#pragma unroll
        for (int i = 0; i < 6; ++i) r3[i] = p3[i];
        const float* p4 = P + PL4 + ab * 36;
#pragma unroll
        for (int i = 0; i < 9; ++i) {
            float4 q = *(const float4*)(p4 + 4 * i);
            r4[4 * i] = q.x; r4[4 * i + 1] = q.y;
            r4[4 * i + 2] = q.z; r4[4 * i + 3] = q.w;
        }
    }

    for (int r = 1; r < R; ++r) {
        const float* U = base + (size_t)r * PSTRIDE;
        // B1 (6) and B2 (36) into registers
        float b1[6], b2[36];
        {
            float4 q = *(const float4*)(U + PL1);
            float2 p = *(const float2*)(U + PL1 + 4);
            b1[0] = q.x; b1[1] = q.y; b1[2] = q.z; b1[3] = q.w;
            b1[4] = p.x; b1[5] = p.y;
        }
#pragma unroll
        for (int i = 0; i < 9; ++i) {
            float4 q = *(const float4*)(U + PL2 + 4 * i);
            b2[4 * i] = q.x; b2[4 * i + 1] = q.y;
            b2[4 * i + 2] = q.z; b2[4 * i + 3] = q.w;
        }
        // B3 row ab (6) for T3
        float b3r[6];
        {
            const float* p = U + PL3 + ab * 6;
            float2 u0 = *(const float2*)(p + 0);
            float2 u1 = *(const float2*)(p + 2);
            float2 u2 = *(const float2*)(p + 4);
            b3r[0] = u0.x; b3r[1] = u0.y; b3r[2] = u1.x;
            b3r[3] = u1.y; b3r[4] = u2.x; b3r[5] = u2.y;
        }
        // T4: stream B4 row ab and B3 row b quad-by-quad (old r3,r2,s1)
        const float* p4g = U + PL4 + ab * 36;
        const float* p3g = U + PL3 + b * 36;
#pragma unroll
        for (int i = 0; i < 9; ++i) {
            float4 f4 = *(const float4*)(p4g + 4 * i);
            float4 f3 = *(const float4*)(p3g + 4 * i);
            float bv4[4] = {f4.x, f4.y, f4.z, f4.w};
            float bv3[4] = {f3.x, f3.y, f3.z, f3.w};
#pragma unroll
            for (int k = 0; k < 4; ++k) {
                const int cd = 4 * i + k, cc = cd / 6, d = cd - cc * 6;
                float v = r4[cd] + bv4[k];
                v = fmaf(r3[cc], b1[d], v);
                v = fmaf(r2, b2[cd], v);
                r4[cd] = fmaf(s1, bv3[k], v);
            }
        }
        // T3 (old r2, s1)
#pragma unroll
        for (int cc = 0; cc < 6; ++cc) {
            float v = r3[cc] + b3r[cc];
            v = fmaf(r2, b1[cc], v);
            r3[cc] = fmaf(s1, b2[b * 6 + cc], v);
        }
        // T2, T1
        r2 = fmaf(s1, b1[b], r2 + b2[ab]);
        s1 += b1[a];
    }

    if (t < 36) {
        if (flat_out) {
            float* O = out;              // flat 1554: L1@0 L2@6 L3@42 L4@258
            if (a == b) O[a] = s1;
            O[6 + ab] = r2;
            float* o3 = O + 42 + ab * 6;
            *(float2*)(o3 + 0) = make_float2(r3[0], r3[1]);
            *(float2*)(o3 + 2) = make_float2(r3[2], r3[3]);
            *(float2*)(o3 + 4) = make_float2(r3[4], r3[5]);
            float* o4 = O + 258 + ab * 36;   // 8B-aligned
#pragma unroll
            for (int i = 0; i < 18; ++i)
                *(float2*)(o4 + 2 * i) = make_float2(r4[2 * i], r4[2 * i + 1]);
        } else {
            float* P = out + (size_t)blockIdx.x * PSTRIDE;
            if (a == b) P[PL1 + a] = s1;
            P[PL2 + ab] = r2;
            float* p3 = P + PL3 + ab * 6;
            *(float2*)(p3 + 0) = make_float2(r3[0], r3[1]);
            *(float2*)(p3 + 2) = make_float2(r3[2], r3[3]);
            *(float2*)(p3 + 4) = make_float2(r3[4], r3[5]);
            float* p4 = P + PL4 + ab * 36;
#pragma unroll
            for (int i = 0; i < 9; ++i)
                *(float4*)(p4 + 4 * i) =
                    make_float4(r4[4 * i], r4[4 * i + 1], r4[4 * i + 2], r4[4 * i + 3]);
        }
    }
}

// ---------------------------------------------------------------------------
extern "C" void kernel_launch(void* const* d_in, const int* in_sizes, int n_in,
                              void* d_out, int out_size, void* d_ws, size_t ws_size,
                              hipStream_t stream) {
    const float* x = (const float*)d_in[0];
    float* out = (float*)d_out;
    float* ws0 = (float*)d_ws;                         // 1024 padded partials
    float* ws1 = ws0 + (size_t)NCHUNK * PSTRIDE;       // 32 padded partials

    sig_fold<<<NCHUNK, 64, 0, stream>>>(x, ws0);
    sig_comb<<<32, 64, 0, stream>>>(ws0, ws1, 32, 0);  // 1024 -> 32
    sig_comb<<<1, 64, 0, stream>>>(ws1, out, 32, 1);   // 32 -> 1
}

// Round 4
// 100.976 us; speedup vs baseline: 2.4677x; 2.4677x over previous
//
#include <hip/hip_runtime.h>

#define DIM 6
#define NSEG 65535
#define CH 64            // segments per chunk
#define NCHUNK 1024      // NCHUNK*CH >= NSEG

// Padded partial-signature layout (per chunk), stride in floats.
// 16B-aligned sections: L1@0(6), L2@8(36), L3@48(216), L4@264(1296)
#define PSTRIDE 1568
#define PL1 0
#define PL2 8
#define PL3 48
#define PL4 264
#define NGRP 259         // 1 + 6 + 36 + 216 output groups of 6

// ---------------- Kernel 1: one wave per chunk, register-resident Chen fold -
// Lane t<36 owns pair ab=t (a=ab/6, b=ab%6): S4 row (36 regs), S3 row (6),
// S2[ab] (1), private S1[a] (1).  NO dynamic indexing of register arrays:
// lane-dependent dx_a/dx_b come from lane-addressed LDS reads.
__global__ __launch_bounds__(64) void sig_fold(const float* __restrict__ x,
                                               float* __restrict__ part) {
    __shared__ float dxs[CH * 8];   // dx row j at 8-float stride
    const int t = threadIdx.x;
    const int c = blockIdx.x;
    const int j0 = c * CH;
    const int cnt = min(CH, NSEG - j0);    // 64, or 63 for the last chunk

    for (int f = t; f < CH * 8; f += 64) dxs[f] = 0.f;
    __syncthreads();
    const float* xb = x + (size_t)j0 * DIM;
    for (int f = t; f < cnt * DIM; f += 64) {
        int j = f / 6, k = f - j * 6;
        dxs[j * 8 + k] = xb[f + 6] - xb[f];
    }
    __syncthreads();

    const int ab = (t < 36) ? t : 35;
    const int a = ab / 6, b = ab - a * 6;
    const float* dxap = dxs + a;    // lane-varying LDS bases
    const float* dxbp = dxs + b;

    float r4[36], r3[6], r2 = 0.f, s1 = 0.f;
#pragma unroll
    for (int i = 0; i < 36; ++i) r4[i] = 0.f;
#pragma unroll
    for (int i = 0; i < 6; ++i) r3[i] = 0.f;

#pragma unroll 2
    for (int j = 0; j < CH; ++j) {
        const float4 q0 = *(const float4*)(dxs + j * 8);
        const float2 q1 = *(const float2*)(dxs + j * 8 + 4);
        const float dxv[6] = {q0.x, q0.y, q0.z, q0.w, q1.x, q1.y}; // const-idx only
        const float dxa = dxap[j * 8];   // ds_read lane-addressed
        const float dxb = dxbp[j * 8];

        // t2 = S2 + dx_b*(S1/3 + dx_a/12)            (old S2, S1)
        float t2 = fmaf(dxb, fmaf(dxa, (1.f / 12.f), s1 * (1.f / 3.f)), r2);
        float t2h = 0.5f * t2;                        // *0.5 is exact
        // S4[cd] += (S3[c] + t2*0.5*dx[c]) * dx[d]   (old S3)
        float w[6];
#pragma unroll
        for (int cc = 0; cc < 6; ++cc) w[cc] = fmaf(t2h, dxv[cc], r3[cc]);
#pragma unroll
        for (int cc = 0; cc < 6; ++cc)
#pragma unroll
            for (int d = 0; d < 6; ++d)
                r4[cc * 6 + d] = fmaf(w[cc], dxv[d], r4[cc * 6 + d]);
        // S3[c] += (S2 + t3*0.5*dx_b) * dx[c],  t3 = S1 + dx_a/3
        float t3 = fmaf(dxa, (1.f / 3.f), s1);
        float v = fmaf(0.5f * t3, dxb, r2);
#pragma unroll
        for (int cc = 0; cc < 6; ++cc) r3[cc] = fmaf(v, dxv[cc], r3[cc]);
        // S2 += (S1 + 0.5*dx_a) * dx_b ; S1 += dx_a
        r2 = fmaf(fmaf(0.5f, dxa, s1), dxb, r2);
        s1 += dxa;
    }

    if (t < 36) {
        float* P = part + (size_t)c * PSTRIDE;
        if (a == b) P[PL1 + a] = s1;
        P[PL2 + ab] = r2;
        float* p3 = P + PL3 + ab * 6;
        *(float2*)(p3 + 0) = make_float2(r3[0], r3[1]);
        *(float2*)(p3 + 2) = make_float2(r3[2], r3[3]);
        *(float2*)(p3 + 4) = make_float2(r3[4], r3[5]);
        float* p4 = P + PL4 + ab * 36;
#pragma unroll
        for (int i = 0; i < 9; ++i)
            *(float4*)(p4 + 4 * i) =
                make_float4(r4[4 * i], r4[4 * i + 1], r4[4 * i + 2], r4[4 * i + 3]);
    }
}

// ---------------- Chen pair-combine helpers (padded layout) -----------------
// Group g: 0 -> L1; 1..6 -> L2 row a; 7..42 -> L3 row ab; 43..258 -> L4 row abc.
// A,B are padded 1568-float signatures (global or LDS via generic pointer).
__device__ __forceinline__ void chen_vals(const float* __restrict__ A,
                                          const float* __restrict__ B,
                                          int g, float* v) {
    if (g == 0) {
#pragma unroll
        for (int d = 0; d < 6; ++d) v[d] = A[PL1 + d] + B[PL1 + d];
    } else if (g < 7) {
        int a = g - 1;
        float a1 = A[PL1 + a];
        const float* Ar = A + PL2 + a * 6;
        const float* Br = B + PL2 + a * 6;
#pragma unroll
        for (int d = 0; d < 6; ++d) v[d] = Ar[d] + Br[d] + a1 * B[PL1 + d];
    } else if (g < 43) {
        int ab = g - 7, a = ab / 6, b = ab - a * 6;
        float a2 = A[PL2 + ab], a1 = A[PL1 + a];
        const float* Ar = A + PL3 + ab * 6;
        const float* Br = B + PL3 + ab * 6;
        const float* B2r = B + PL2 + b * 6;
#pragma unroll
        for (int d = 0; d < 6; ++d)
            v[d] = Ar[d] + Br[d] + a2 * B[PL1 + d] + a1 * B2r[d];
    } else {
        int abc = g - 43, ab = abc / 6, cc = abc - ab * 6, a = abc / 36,
            bc = abc - a * 36;
        float a3 = A[PL3 + abc], a2 = A[PL2 + ab], a1 = A[PL1 + a];
        const float* Ar = A + PL4 + abc * 6;
        const float* Br = B + PL4 + abc * 6;
        const float* B2r = B + PL2 + cc * 6;
        const float* B3r = B + PL3 + bc * 6;
#pragma unroll
        for (int d = 0; d < 6; ++d)
            v[d] = Ar[d] + Br[d] + a3 * B[PL1 + d] + a2 * B2r[d] + a1 * B3r[d];
    }
}

__device__ __forceinline__ int grp_off_padded(int g) {
    if (g == 0) return PL1;
    if (g < 7) return PL2 + (g - 1) * 6;
    if (g < 43) return PL3 + (g - 7) * 6;
    return PL4 + (g - 43) * 6;
}
__device__ __forceinline__ int grp_off_flat(int g) {
    if (g == 0) return 0;
    if (g < 7) return 6 + (g - 1) * 6;
    if (g < 43) return 42 + (g - 7) * 6;
    return 258 + (g - 43) * 6;
}

__device__ __forceinline__ void write_final(float* out, int flat_out, int g,
                                            const float* v, int blk) {
    if (flat_out) {
        int off = grp_off_flat(g);
#pragma unroll
        for (int d = 0; d < 6; ++d) out[off + d] = v[d];
    } else {
        float* O = out + (size_t)blk * PSTRIDE;
        int off = grp_off_padded(g);
#pragma unroll
        for (int d = 0; d < 6; ++d) O[off + d] = v[d];
    }
}

// ---------------- Kernel 2: radix-gs in-block Chen tree (gs in {2,8}) -------
__global__ __launch_bounds__(256) void sig_tree(const float* __restrict__ in,
                                                float* __restrict__ out,
                                                int gs, int flat_out) {
    __shared__ float buf0[4 * PSTRIDE];   // 25.1 KB
    __shared__ float buf1[2 * PSTRIDE];   // 12.5 KB
    const int t = threadIdx.x;
    const float* gbase = in + (size_t)blockIdx.x * gs * PSTRIDE;

    int np = gs >> 1;
    // level 0: pairs read directly from global (L2-hot)
    for (int idx = t; idx < np * NGRP; idx += 256) {
        int p = idx / NGRP, g = idx - p * NGRP;
        const float* A = gbase + (size_t)(2 * p) * PSTRIDE;
        float v[6];
        chen_vals(A, A + PSTRIDE, g, v);
        if (np == 1) {
            write_final(out, flat_out, g, v, blockIdx.x);
        } else {
            float* o = buf0 + p * PSTRIDE + grp_off_padded(g);
#pragma unroll
            for (int d = 0; d < 6; ++d) o[d] = v[d];
        }
    }
    if (np == 1) return;

    float* cur = buf0;
    float* nxt = buf1;
    while (np > 1) {
        __syncthreads();
        np >>= 1;
        for (int idx = t; idx < np * NGRP; idx += 256) {
            int p = idx / NGRP, g = idx - p * NGRP;
            const float* A = cur + (2 * p) * PSTRIDE;
            float v[6];
            chen_vals(A, A + PSTRIDE, g, v);
            if (np == 1) {
                write_final(out, flat_out, g, v, blockIdx.x);
            } else {
                float* o = nxt + p * PSTRIDE + grp_off_padded(g);
#pragma unroll
                for (int d = 0; d < 6; ++d) o[d] = v[d];
            }
        }
        float* tmp = cur; cur = nxt; nxt = tmp;
    }
}

// ---------------------------------------------------------------------------
extern "C" void kernel_launch(void* const* d_in, const int* in_sizes, int n_in,
                              void* d_out, int out_size, void* d_ws, size_t ws_size,
                              hipStream_t stream) {
    const float* x = (const float*)d_in[0];
    float* out = (float*)d_out;
    float* ws0 = (float*)d_ws;                          // 1024 padded partials
    float* ws1 = ws0 + (size_t)NCHUNK * PSTRIDE;        // 128
    float* ws2 = ws1 + (size_t)128 * PSTRIDE;           // 16
    float* ws3 = ws2 + (size_t)16 * PSTRIDE;            // 2

    sig_fold<<<NCHUNK, 64, 0, stream>>>(x, ws0);
    sig_tree<<<128, 256, 0, stream>>>(ws0, ws1, 8, 0);  // 1024 -> 128
    sig_tree<<<16, 256, 0, stream>>>(ws1, ws2, 8, 0);   // 128  -> 16
    sig_tree<<<2, 256, 0, stream>>>(ws2, ws3, 8, 0);    // 16   -> 2
    sig_tree<<<1, 256, 0, stream>>>(ws3, out, 2, 1);    // 2    -> 1
}